// Round 1
// baseline (339.989 us; speedup 1.0000x reference)
//
#include <hip/hip_runtime.h>

namespace {

constexpr int V    = 200;
constexpr int F    = 64;
constexpr int FOUT = 64;
constexpr int VP   = 208;   // V padded to 16*13 so 16 v-groups x 13 rows covers it
constexpr int UT   = 8;     // u-tile

__device__ __forceinline__ void fma4(float4& o, float s, const float4& t) {
    o.x += s * t.x; o.y += s * t.y; o.z += s * t.z; o.w += s * t.w;
}

// One workgroup per (n,t). 256 threads = 16 v-groups (13 rows each, padded) x
// 16 f-groups (4 cols each). LDS: x tile 50 KB (reused for y in epilogue) +
// two 8x208 coefficient tiles + d. Total 65,344 B <= 64 KiB static limit.
__global__ __launch_bounds__(256, 2)
void cheb_kernel(const float* __restrict__ x,
                 const float* __restrict__ Att,
                 const float* __restrict__ S,
                 const float* __restrict__ Theta,
                 float* __restrict__ out)
{
    __shared__ __align__(16) float xs[V * F];   // 51,200 B: x tile, later y tile
    __shared__ float B1[UT * VP];               // 6,656 B
    __shared__ float B2[UT * VP];               // 6,656 B
    __shared__ float d_lds[VP];                 // 832 B

    const int tid = threadIdx.x;
    const int b   = blockIdx.x;      // 0..511 = (n,t)
    const int n   = b >> 6;

    const float* __restrict__ Sp = S   + (size_t)b * (V * V);
    const float* __restrict__ Ap = Att + (size_t)n * (V * V);
    const float* __restrict__ xp = x   + (size_t)b * (V * F);
    float* __restrict__       op = out + (size_t)b * (V * FOUT);

    // ---- stage x[n,t,:,:] into LDS (coalesced float4) ----
    for (int i = tid; i < V * F / 4; i += 256)
        ((float4*)xs)[i] = ((const float4*)xp)[i];

    // ---- d[v] = sum_u min(S[u,v], S[v,u])  (S_min is symmetric) ----
    if (tid < V) {
        const int v = tid;
        float s = 0.f;
        #pragma unroll 4
        for (int u = 0; u < V; ++u)
            s += fminf(Sp[u * V + v], Sp[v * V + u]);
        d_lds[v] = s;
    }
    // visibility of xs and d_lds covered by the barrier at top of the u-loop

    const int vg = tid >> 4;       // 0..15
    const int fg = tid & 15;       // 0..15
    const int v0 = vg * 13;        // 0..195
    const int f0 = fg * 4;

    float4 y1[13], y2[13];
    #pragma unroll
    for (int j = 0; j < 13; ++j) {
        y1[j] = make_float4(0.f, 0.f, 0.f, 0.f);
        y2[j] = make_float4(0.f, 0.f, 0.f, 0.f);
    }

    // ---- main loop over u-tiles: build B1/B2 coefficients, then FMA ----
    for (int u0 = 0; u0 < V; u0 += UT) {
        __syncthreads();   // previous tile fully consumed (and first-iter: xs/d ready)
        for (int e = tid; e < UT * VP; e += 256) {
            const int ul = e / VP;          // magic-mul division
            const int v  = e - ul * VP;
            const int u  = u0 + ul;
            float b1 = 0.f, b2 = 0.f;
            if (v < V) {
                const float m  = fminf(Sp[u * V + v], Sp[v * V + u]);
                const float at = Ap[u * V + v];
                if (u == v) {
                    const float c = d_lds[u] - 1.0f - m;  // L_t diag
                    b1 = c * at;
                    b2 = (2.0f * c * c - 1.0f) * at;      // (2*Lt^2 - 1)*Att
                } else {
                    b1 = -m * at;                          // Lt offdiag = -S_min
                    b2 = (2.0f * m * m) * at;              // 2*Lt^2*Att
                }
            }
            B1[e] = b1;
            B2[e] = b2;
        }
        __syncthreads();
        #pragma unroll
        for (int ul = 0; ul < UT; ++ul) {
            const float4 xv = *(const float4*)&xs[(u0 + ul) * F + f0];
            #pragma unroll
            for (int j = 0; j < 13; ++j) {
                const float b1v = B1[ul * VP + v0 + j];
                const float b2v = B2[ul * VP + v0 + j];
                fma4(y1[j], b1v, xv);
                fma4(y2[j], b2v, xv);
            }
        }
    }

    // ---- epilogue: out[v,fo] = relu( Att[v,v]*(x@T0) + y1@T1 + y2@T2 ) ----
    float4 o[13];
    #pragma unroll
    for (int j = 0; j < 13; ++j) o[j] = make_float4(0.f, 0.f, 0.f, 0.f);

    // Theta contraction from xs into o (o[j] += xs[v,:] @ Th[:, f0..f0+3]).
    // f4 staggered by vg so the 4 vg's in a wave hit different LDS banks.
    auto contract = [&](const float* __restrict__ Th) {
        for (int i4 = 0; i4 < 16; ++i4) {
            const int f4 = 4 * ((i4 + vg * 4) & 15);
            const float4 t0 = *(const float4*)&Th[(f4 + 0) * FOUT + f0];
            const float4 t1 = *(const float4*)&Th[(f4 + 1) * FOUT + f0];
            const float4 t2 = *(const float4*)&Th[(f4 + 2) * FOUT + f0];
            const float4 t3 = *(const float4*)&Th[(f4 + 3) * FOUT + f0];
            #pragma unroll
            for (int j = 0; j < 13; ++j) {
                int v = v0 + j; if (v > V - 1) v = V - 1;  // clamp pad rows
                const float4 xv = *(const float4*)&xs[v * F + f4];
                fma4(o[j], xv.x, t0); fma4(o[j], xv.y, t1);
                fma4(o[j], xv.z, t2); fma4(o[j], xv.w, t3);
            }
        }
    };

    // k = 0: xs still holds x; contract with Theta0 then scale by Att diag
    contract(Theta);
    #pragma unroll
    for (int j = 0; j < 13; ++j) {
        const int v = v0 + j;
        const float av = (v < V) ? Ap[v * V + v] : 0.f;
        o[j].x *= av; o[j].y *= av; o[j].z *= av; o[j].w *= av;
    }

    // k = 1, 2: round-trip y_k through xs, contract with Theta_k
    #pragma unroll
    for (int k = 1; k <= 2; ++k) {
        __syncthreads();   // previous reads of xs done
        #pragma unroll
        for (int j = 0; j < 13; ++j) {
            const int v = v0 + j;
            if (v < V)
                *(float4*)&xs[v * F + f0] = (k == 1) ? y1[j] : y2[j];
        }
        __syncthreads();
        contract(Theta + k * (F * FOUT));
    }

    // ---- relu + store (coalesced float4) ----
    #pragma unroll
    for (int j = 0; j < 13; ++j) {
        const int v = v0 + j;
        if (v < V) {
            float4 r = o[j];
            r.x = fmaxf(r.x, 0.f); r.y = fmaxf(r.y, 0.f);
            r.z = fmaxf(r.z, 0.f); r.w = fmaxf(r.w, 0.f);
            *(float4*)&op[v * FOUT + f0] = r;
        }
    }
}

} // namespace

extern "C" void kernel_launch(void* const* d_in, const int* in_sizes, int n_in,
                              void* d_out, int out_size, void* d_ws, size_t ws_size,
                              hipStream_t stream) {
    const float* x     = (const float*)d_in[0];
    const float* Att   = (const float*)d_in[1];
    const float* S     = (const float*)d_in[2];
    const float* Theta = (const float*)d_in[3];
    float* out         = (float*)d_out;

    hipLaunchKernelGGL(cheb_kernel, dim3(8 * 64), dim3(256), 0, stream,
                       x, Att, S, Theta, out);
}